// Round 6
// baseline (942.824 us; speedup 1.0000x reference)
//
#include <hip/hip_runtime.h>

// RNN scan: T=750 sequential steps, x[B=1024,H=100].
//   r = tanh(x); x += ALPHA*(-x + r@J^T + u@b_in^T + c_x + 0.1*n)
// Structure: 1 batch element per block, 112 threads (1.75 waves), 1024 blocks
// -> 4 blocks/CU, 8 waves/CU. Narrow barriers (2 waves); 4 independent
// recurrences per CU overlap each other's serial tails.
// J row h held in 25 NAMED float4 (100 VGPRs) -- no arrays, no runtime
// indexing; each scalar component asm-pinned (float4 tied asm operands are
// not supported by the backend -- R5 compile failure) so the values can be
// neither SROA-dropped to scratch nor rematerialized as in-loop loads.

typedef float v2f __attribute__((ext_vector_type(2)));

#define TSTEPS 750
#define BATCH  1024
#define HID    100
#define THREADS 112

constexpr float ALPHA = 0.1f;   // DT/TAU
constexpr float NSTD  = 0.1f;

#define REP25(X) X(0)X(1)X(2)X(3)X(4)X(5)X(6)X(7)X(8)X(9)X(10)X(11)X(12) \
                 X(13)X(14)X(15)X(16)X(17)X(18)X(19)X(20)X(21)X(22)X(23)X(24)

__device__ __forceinline__ float ftanh(float x) {
    // tanh(x) = 1 - 2/(exp(2x)+1)
    float e = __expf(2.0f * x);
    return 1.0f - 2.0f * __builtin_amdgcn_rcpf(e + 1.0f);
}

__global__ __launch_bounds__(THREADS, 2) void rnn_scan_kernel(
    const float* __restrict__ input_seq,  // [T,B,4]
    const float* __restrict__ noise,      // [T,B,H]
    const float* __restrict__ J_w,        // [H,H]
    const float* __restrict__ b_in,       // [H,4]
    const float* __restrict__ c_x,        // [H]
    float* __restrict__ states)           // [T,B,H]
{
    const int tid = threadIdx.x;
    const bool act = (tid < HID);
    const int h = act ? tid : (HID - 1);   // clamp idle lanes (stores masked)
    const int b = blockIdx.x;

    // ---- J row h in 25 named float4 = 100 VGPRs ----
    const float4* Jrow = reinterpret_cast<const float4*>(J_w + (size_t)h * HID);
#define DECLJ(i) float4 J##i = Jrow[i];
    REP25(DECLJ)
#undef DECLJ
    // Pin per scalar component: asm-defined scalars are not rematerializable
    // and not SROA-fragile. (float4 tied asm operands fail to compile.)
#define PINJ(i) asm volatile("" : "+v"(J##i.x), "+v"(J##i.y), "+v"(J##i.z), "+v"(J##i.w));
    REP25(PINJ)
#undef PINJ

    const float4 bin = *reinterpret_cast<const float4*>(b_in + (size_t)h * 4);
    const float cx = c_x[h];

    __shared__ __align__(16) float r_lds[2][HID];

    float x = 0.0f;
    if (act) r_lds[0][h] = 0.0f;  // r(x0) = tanh(0) = 0

    const float* uptr = input_seq + (size_t)b * 4;
    const float* nptr = noise + (size_t)b * HID + h;
    float4 u  = *reinterpret_cast<const float4*>(uptr);   // t=0
    float  nz = *nptr;

    float* sptr = states + (size_t)b * HID + h;

    __syncthreads();

    for (int t = 0; t < TSTEPS; ++t) {
        // Prefetch t+1 inputs at loop top; the whole step's compute covers the
        // latency, the pre-barrier vmcnt drain just collects the remainder.
        const int tn = (t + 1 < TSTEPS) ? (t + 1) : t;
        float4 u_next  = *reinterpret_cast<const float4*>(uptr + (size_t)tn * BATCH * 4);
        float  nz_next = nptr[(size_t)tn * BATCH * HID];

        // x_new[h] = sum_k r[k]*J[h,k], k-packed v_pk_fma_f32, 4 chains.
        // r reads are wave-uniform -> LDS broadcast, conflict-free.
        const float4* rb4 = reinterpret_cast<const float4*>(&r_lds[t & 1][0]);
        v2f a0, a1, a2, a3;
        a0.x = bin.x * u.x; a0.y = bin.y * u.y;   // fold u@b_in into chains
        a1.x = bin.z * u.z; a1.y = bin.w * u.w;
        a2.x = 0.f; a2.y = 0.f;
        a3.x = cx;  a3.y = NSTD * nz;
#define DOT(i) { float4 r4 = rb4[i];                                          \
        v2f j01; j01.x = J##i.x; j01.y = J##i.y;                              \
        v2f j23; j23.x = J##i.z; j23.y = J##i.w;                              \
        v2f r01; r01.x = r4.x; r01.y = r4.y;                                  \
        v2f r23; r23.x = r4.z; r23.y = r4.w;                                  \
        if ((i) & 1) { a2 = __builtin_elementwise_fma(j01, r01, a2);          \
                       a3 = __builtin_elementwise_fma(j23, r23, a3); }        \
        else         { a0 = __builtin_elementwise_fma(j01, r01, a0);          \
                       a1 = __builtin_elementwise_fma(j23, r23, a1); } }
        REP25(DOT)
#undef DOT
        v2f av = (a0 + a1) + (a2 + a3);
        float pre = av.x + av.y;              // = r@J + u@b_in + cx + NSTD*nz

        x += ALPHA * (pre - x);               // x += a*(-x + pre)

        float r = ftanh(x);
        if (act) {
            r_lds[(t + 1) & 1][h] = r;                 // next r, alt buffer
            sptr[(size_t)t * BATCH * HID] = x;         // states[t,b,h]
        }

        u = u_next; nz = nz_next;
        __syncthreads();  // 2-wave barrier; other 3 blocks on the CU keep issuing
    }
}

// Readout: out[b,0] = tanh(states[0,b,:]).wout + wb ; out[b,1] = same at T-1.
__global__ __launch_bounds__(64) void rnn_out_kernel(
    const float* __restrict__ states,
    const float* __restrict__ wout_w,
    const float* __restrict__ wout_b,
    float* __restrict__ out)
{
    const int b = blockIdx.x;
    const int l = threadIdx.x;
    const float* s0 = states + (size_t)b * HID;
    const float* sF = states + ((size_t)(TSTEPS - 1) * BATCH + b) * HID;

    float p0 = 0.f, pF = 0.f;
    if (l < HID) {
        p0 = ftanh(s0[l]) * wout_w[l];
        pF = ftanh(sF[l]) * wout_w[l];
    }
    const int l2 = l + 64;
    if (l2 < HID) {
        p0 += ftanh(s0[l2]) * wout_w[l2];
        pF += ftanh(sF[l2]) * wout_w[l2];
    }
#pragma unroll
    for (int off = 32; off > 0; off >>= 1) {
        p0 += __shfl_xor(p0, off, 64);
        pF += __shfl_xor(pF, off, 64);
    }
    if (l == 0) {
        const float wb = wout_b[0];
        out[b * 2 + 0] = p0 + wb;
        out[b * 2 + 1] = pF + wb;
    }
}

extern "C" void kernel_launch(void* const* d_in, const int* in_sizes, int n_in,
                              void* d_out, int out_size, void* d_ws, size_t ws_size,
                              hipStream_t stream) {
    const float* input_seq = (const float*)d_in[0];
    const float* noise     = (const float*)d_in[1];
    const float* J_w       = (const float*)d_in[2];
    const float* b_in      = (const float*)d_in[3];
    const float* c_x       = (const float*)d_in[4];
    const float* wout_w    = (const float*)d_in[5];
    const float* wout_b    = (const float*)d_in[6];

    float* out    = (float*)d_out;       // [B,2]
    float* states = out + 2 * BATCH;     // [T,B,H]

    rnn_scan_kernel<<<BATCH, THREADS, 0, stream>>>(
        input_seq, noise, J_w, b_in, c_x, states);
    rnn_out_kernel<<<BATCH, 64, 0, stream>>>(states, wout_w, wout_b, out);
}

// Round 7
// 635.909 us; speedup vs baseline: 1.4826x; 1.4826x over previous
//
#include <hip/hip_runtime.h>

// RNN scan: T=750 sequential steps, x[B=1024,H=100].
//   r = tanh(x); x += ALPHA*(-x + r@J^T + u@b_in^T + c_x + 0.1*n)
// Structure: 2 threads per h (tid=2h+half), each holding HALF a J row
// (13 float4 = 52 VGPRs) so total register demand (~90) fits what the
// allocator will actually keep (R1-R6: 100/thread always spilled; R2
// showed 128 is allocatable). Pair partial dots combined via shfl_xor(1)
// (in-wave, no barrier). 224-thread blocks, 1 batch/block, 1024 blocks ->
// 4 blocks/CU. Raw s_barrier + lgkmcnt(0) (no vmcnt drain) so the 2-deep
// noise/u prefetch stays in flight across steps.

typedef float v2f __attribute__((ext_vector_type(2)));

#define TSTEPS 750
#define BATCH  1024
#define HID    100
#define THREADS 224   // 200 active (2 per h), 3.5 waves

constexpr float ALPHA = 0.1f;   // DT/TAU
constexpr float NSTD  = 0.1f;

#define REP13(X) X(0)X(1)X(2)X(3)X(4)X(5)X(6)X(7)X(8)X(9)X(10)X(11)X(12)

__device__ __forceinline__ float ftanh(float x) {
    // tanh(x) = 1 - 2/(exp(2x)+1)
    float e = __expf(2.0f * x);
    return 1.0f - 2.0f * __builtin_amdgcn_rcpf(e + 1.0f);
}

__global__ __launch_bounds__(THREADS, 4) void rnn_scan_kernel(
    const float* __restrict__ input_seq,  // [T,B,4]
    const float* __restrict__ noise,      // [T,B,H]
    const float* __restrict__ J_w,        // [H,H]
    const float* __restrict__ b_in,       // [H,4]
    const float* __restrict__ c_x,        // [H]
    float* __restrict__ states)           // [T,B,H]
{
    const int tid = threadIdx.x;
    const bool act  = (tid < 2 * HID);
    const int  t2   = act ? tid : (2 * HID - 1);  // clamp idle lanes
    const int  h    = t2 >> 1;                    // 0..99
    const int  half = t2 & 1;                     // which k-half of row h
    const int  b    = blockIdx.x;
    const bool eact = act && (half == 0);         // the lane that owns x[h]

    // J row h, half k-range: half0 covers k=0..51, half1 covers k=48..99
    // (13 float4 each, 16B-aligned bases; half1 zeroes its first quad so the
    // overlap k=48..51 is counted once). 52 VGPRs -- small enough to stay.
    const float4* jb4 = reinterpret_cast<const float4*>(J_w + (size_t)h * HID + half * 48);
#define DECLJ(q) float4 J##q = jb4[q];
    REP13(DECLJ)
#undef DECLJ
    if (half) { J0.x = 0.f; J0.y = 0.f; J0.z = 0.f; J0.w = 0.f; }

    // Per-h constants, masked to half0 so the pair-sum counts them once.
    float4 bin = *reinterpret_cast<const float4*>(b_in + (size_t)h * 4);
    const float hm = (half == 0) ? 1.0f : 0.0f;
    bin.x *= hm; bin.y *= hm; bin.z *= hm; bin.w *= hm;
    const float cxm   = c_x[h] * hm;
    const float nstdm = NSTD * hm;

    __shared__ __align__(16) float r_lds[2][HID];

    if (eact) r_lds[0][h] = 0.0f;   // r(x0) = tanh(0) = 0

    const float* uptr = input_seq + (size_t)b * 4;
    const float* nptr = noise + (size_t)b * HID + h;
    float* sptr = states + (size_t)b * HID + h;

    float x = 0.0f;  // both lanes of a pair track x[h] redundantly (stay in sync)

    // 2-deep prefetch; raw barriers below don't drain vmcnt, so these
    // genuinely stay in flight across steps.
    float  nz0 = nptr[0];
    float  nz1 = nptr[(size_t)1 * BATCH * HID];
    float4 u0  = *reinterpret_cast<const float4*>(uptr);
    float4 u1  = *reinterpret_cast<const float4*>(uptr + (size_t)1 * BATCH * 4);

    __syncthreads();  // once, covers the r_lds init

#pragma unroll 2
    for (int t = 0; t < TSTEPS; ++t) {
        const int tn = (t + 2 < TSTEPS) ? (t + 2) : (TSTEPS - 1);
        float  nz2 = nptr[(size_t)tn * BATCH * HID];
        float4 u2  = *reinterpret_cast<const float4*>(uptr + (size_t)tn * BATCH * 4);

        // r reads: per wave, 2 distinct addresses (half0/half1 bases) hitting
        // disjoint bank sets -> broadcast, conflict-free.
        const float4* rb4 = reinterpret_cast<const float4*>(&r_lds[t & 1][0] + half * 48);

        v2f a0, a1, a2, a3;   // 4 chains; u@b_in, cx, noise folded (half0 only)
        a0.x = bin.x * u0.x; a0.y = bin.y * u0.y;
        a1.x = bin.z * u0.z; a1.y = bin.w * u0.w;
        a2.x = 0.f;          a2.y = 0.f;
        a3.x = cxm;          a3.y = nstdm * nz0;
#define DOT(q) { float4 r4 = rb4[q];                                          \
        v2f j01; j01.x = J##q.x; j01.y = J##q.y;                              \
        v2f j23; j23.x = J##q.z; j23.y = J##q.w;                              \
        v2f r01; r01.x = r4.x; r01.y = r4.y;                                  \
        v2f r23; r23.x = r4.z; r23.y = r4.w;                                  \
        if ((q) & 1) { a2 = __builtin_elementwise_fma(j01, r01, a2);          \
                       a3 = __builtin_elementwise_fma(j23, r23, a3); }        \
        else         { a0 = __builtin_elementwise_fma(j01, r01, a0);          \
                       a1 = __builtin_elementwise_fma(j23, r23, a1); } }
        REP13(DOT)
#undef DOT
        v2f av = (a0 + a1) + (a2 + a3);
        float sp = av.x + av.y;
        float s  = sp + __shfl_xor(sp, 1, 64);  // pair-sum -> full pre-activation

        x += ALPHA * (s - x);
        float r = ftanh(x);

        if (eact) {
            r_lds[(t + 1) & 1][h] = r;              // next r, alt buffer
            sptr[(size_t)t * BATCH * HID] = x;      // states[t,b,h]
        }

        nz0 = nz1; nz1 = nz2;
        u0 = u1;   u1 = u2;

        // Raw barrier: wait only LDS ops (r write), leave global loads/stores
        // in flight. LDS-only inter-thread communication makes this legal.
        asm volatile("s_waitcnt lgkmcnt(0)" ::: "memory");
        __builtin_amdgcn_s_barrier();
        __builtin_amdgcn_sched_barrier(0);
    }
}

// Readout: out[b,0] = tanh(states[0,b,:]).wout + wb ; out[b,1] = same at T-1.
__global__ __launch_bounds__(64) void rnn_out_kernel(
    const float* __restrict__ states,
    const float* __restrict__ wout_w,
    const float* __restrict__ wout_b,
    float* __restrict__ out)
{
    const int b = blockIdx.x;
    const int l = threadIdx.x;
    const float* s0 = states + (size_t)b * HID;
    const float* sF = states + ((size_t)(TSTEPS - 1) * BATCH + b) * HID;

    float p0 = 0.f, pF = 0.f;
    if (l < HID) {
        p0 = ftanh(s0[l]) * wout_w[l];
        pF = ftanh(sF[l]) * wout_w[l];
    }
    const int l2 = l + 64;
    if (l2 < HID) {
        p0 += ftanh(s0[l2]) * wout_w[l2];
        pF += ftanh(sF[l2]) * wout_w[l2];
    }
#pragma unroll
    for (int off = 32; off > 0; off >>= 1) {
        p0 += __shfl_xor(p0, off, 64);
        pF += __shfl_xor(pF, off, 64);
    }
    if (l == 0) {
        const float wb = wout_b[0];
        out[b * 2 + 0] = p0 + wb;
        out[b * 2 + 1] = pF + wb;
    }
}

extern "C" void kernel_launch(void* const* d_in, const int* in_sizes, int n_in,
                              void* d_out, int out_size, void* d_ws, size_t ws_size,
                              hipStream_t stream) {
    const float* input_seq = (const float*)d_in[0];
    const float* noise     = (const float*)d_in[1];
    const float* J_w       = (const float*)d_in[2];
    const float* b_in      = (const float*)d_in[3];
    const float* c_x       = (const float*)d_in[4];
    const float* wout_w    = (const float*)d_in[5];
    const float* wout_b    = (const float*)d_in[6];

    float* out    = (float*)d_out;       // [B,2]
    float* states = out + 2 * BATCH;     // [T,B,H]

    rnn_scan_kernel<<<BATCH, THREADS, 0, stream>>>(
        input_seq, noise, J_w, b_in, c_x, states);
    rnn_out_kernel<<<BATCH, 64, 0, stream>>>(states, wout_w, wout_b, out);
}